// Round 10
// baseline (1746.759 us; speedup 1.0000x reference)
//
#include <hip/hip_runtime.h>
#include <hip/hip_bf16.h>

// Problem constants (match reference).
#define VOCAB  50257
#define D_EMB  128
#define HID    256
#define N_CLS  2
#define BSZ    256
#define T_LEN  2048

// ---------------------------------------------------------------------------
// Kernel 1: tab[v][j] = sum_d emb_table[v][d] * wx_w[d][j] + wx_b[j] + wh_b[j]
// ---------------------------------------------------------------------------
__global__ __launch_bounds__(256)
void tabax_kernel(const float* __restrict__ emb,
                  const float* __restrict__ wxw,
                  const float* __restrict__ wxb,
                  const float* __restrict__ whb,
                  float* __restrict__ tab)
{
    const int j  = threadIdx.x;          // output unit 0..255
    const int v0 = blockIdx.x * 32;
    const int rows = min(32, VOCAB - v0);

    __shared__ float ebuf[32 * D_EMB];   // 16 KB
    for (int i = j; i < rows * D_EMB; i += 256)
        ebuf[i] = emb[(size_t)v0 * D_EMB + i];
    __syncthreads();

    float acc[32];
#pragma unroll
    for (int r = 0; r < 32; ++r) acc[r] = 0.f;

#pragma unroll 8
    for (int d = 0; d < D_EMB; ++d) {
        float wxv = wxw[d * HID + j];    // coalesced
#pragma unroll
        for (int r = 0; r < 32; ++r)
            acc[r] = fmaf(ebuf[r * D_EMB + d], wxv, acc[r]); // LDS broadcast
    }

    const float bb = wxb[j] + whb[j];
    for (int r = 0; r < rows; ++r)
        tab[(size_t)(v0 + r) * HID + j] = acc[r] + bb;       // coalesced
}

__device__ __forceinline__ float fast_tanh(float x) {
    float e2 = __expf(2.f * x);
    return 1.f - 2.f / (e2 + 1.f);
}

// VGPR-use-forcing FMA: "v" constraints at EVERY use site inside the hot
// loop make the frequency-aware spiller keep W in VGPRs instead of the
// AGPR stash + per-use v_accvgpr_read that R7/R9 counters implied
// (VGPR_Count=84 with 128 live floats, ~200 unexplained VALU insts/step).
// Non-volatile: schedulable, dead-code-safe via data deps.
#define FMUL_V(ACC, Wv, Hv) \
    asm("v_mul_f32 %0, %1, %2" : "=v"(ACC) : "v"(Wv), "v"(Hv))
#define FMAC_V(ACC, Wv, Hv) \
    asm("v_fmac_f32 %0, %1, %2" : "+v"(ACC) : "v"(Wv), "v"(Hv))

// ---------------------------------------------------------------------------
// Kernel 2 (main): one block per batch row, 512 threads.
// Thread (cg = tid>>4, kg = tid&15) owns cols [cg*8, cg*8+8) over k in
// [kg*16, kg*16+16). Weights W[4][4][8] = 128 f32, pinned once via asm
// value-barrier and consumed by asm v_fmac with "v"-constrained sources.
// Each swizzled ds_read_b128 of h feeds 32 FMAs. k-reduce over 16 lanes =
// sel-pair halving tree. t-loop unrolled x2 (static LDS buffer index).
// Bank swizzle eff=(e+(kg>>2))&3: 2 addrs per bank-quad = conflict-free.
// ---------------------------------------------------------------------------
__global__ __launch_bounds__(512, 1)
void rnn_main_kernel(const int*   __restrict__ batch,
                     const float* __restrict__ whw,
                     const float* __restrict__ clfw,
                     const float* __restrict__ clfb,
                     const float* __restrict__ ax_tab,
                     float*       __restrict__ out)
{
    const int b   = blockIdx.x;
    const int tid = threadIdx.x;
    const int kg  = tid & 15;            // k-group: k in [kg*16, kg*16+16)
    const int cg  = tid >> 4;            // col-group: cols [cg*8, cg*8+8)
    const int c0  = cg * 8;
    const int kb  = kg * 16;
    const int rot = (kg >> 2) & 3;       // bank-swizzle rotation

    __shared__ float hbuf[2][HID];       // double-buffered hidden state
    __shared__ float sbuf[2][HID];       // epilogue scratch

    // --- one-time weight load: W[e][m][i] = wh_w[kb+((e+rot)&3)*4+m][c0+i] ---
    float W[4][4][8];
#pragma unroll
    for (int e = 0; e < 4; ++e) {
        const int swz = (e + rot) & 3;
#pragma unroll
        for (int m = 0; m < 4; ++m) {
            const int k = kb + swz * 4 + m;
            const float4 lo = *(const float4*)&whw[(size_t)k * HID + c0];
            const float4 hi = *(const float4*)&whw[(size_t)k * HID + c0 + 4];
            W[e][m][0] = lo.x; W[e][m][1] = lo.y; W[e][m][2] = lo.z; W[e][m][3] = lo.w;
            W[e][m][4] = hi.x; W[e][m][5] = hi.y; W[e][m][6] = hi.z; W[e][m][7] = hi.w;
        }
    }
    // Pin: asm redefines each value -> no rematerialization possible.
#pragma unroll
    for (int e = 0; e < 4; ++e)
#pragma unroll
        for (int m = 0; m < 4; ++m)
#pragma unroll
            for (int i = 0; i < 8; i += 4)
                asm volatile("" : "+v"(W[e][m][i + 0]), "+v"(W[e][m][i + 1]),
                                  "+v"(W[e][m][i + 2]), "+v"(W[e][m][i + 3]));

    // LDS byte offsets of the 4 swizzled float4 reads (within one h buffer).
    int lds_off[4];
#pragma unroll
    for (int e = 0; e < 4; ++e) lds_off[e] = kg * 64 + ((e + rot) & 3) * 16;

    const int  mycol = c0 + ((kg >> 1) & 7);   // column this lane finalizes
    const bool wr    = (kg & 1) == 0;          // even lane of the pair writes

    if (tid < HID) hbuf[0][tid] = 0.f;

    const int* brow = batch + (size_t)b * T_LEN;
    int tok_n = brow[0];
    float axv = ax_tab[(size_t)tok_n * HID + mycol];   // ax for t=0
    tok_n = brow[1];
    __syncthreads();

#define RNN_STEP(CUR, NXT, TT)                                              \
    {                                                                       \
        const int tok_nn = ((TT) + 2 < T_LEN) ? brow[(TT) + 2] : 0;         \
        const float ax_n = ax_tab[(size_t)tok_n * HID + mycol];             \
        float acc[8];                                                       \
        const char* hb = (const char*)&hbuf[CUR][0];                        \
        {   /* e = 0: first m initializes acc via v_mul */                  \
            const float4 h4 = *(const float4*)(hb + lds_off[0]);            \
            const float hm[4] = {h4.x, h4.y, h4.z, h4.w};                   \
            _Pragma("unroll")                                               \
            for (int i = 0; i < 8; ++i) FMUL_V(acc[i], W[0][0][i], hm[0]);  \
            _Pragma("unroll")                                               \
            for (int m = 1; m < 4; ++m)                                     \
                _Pragma("unroll")                                           \
                for (int i = 0; i < 8; ++i)                                 \
                    FMAC_V(acc[i], W[0][m][i], hm[m]);                      \
        }                                                                   \
        _Pragma("unroll")                                                   \
        for (int e = 1; e < 4; ++e) {                                       \
            const float4 h4 = *(const float4*)(hb + lds_off[e]);            \
            const float hm[4] = {h4.x, h4.y, h4.z, h4.w};                   \
            _Pragma("unroll")                                               \
            for (int m = 0; m < 4; ++m)                                     \
                _Pragma("unroll")                                           \
                for (int i = 0; i < 8; ++i)                                 \
                    FMAC_V(acc[i], W[e][m][i], hm[m]);                      \
        }                                                                   \
        _Pragma("unroll")                                                   \
        for (int i = 0; i < 4; ++i) {              /* mask 8: 8 -> 4 */     \
            const float send = (kg & 8) ? acc[i] : acc[i + 4];              \
            const float keep = (kg & 8) ? acc[i + 4] : acc[i];              \
            acc[i] = keep + __shfl_xor(send, 8);                            \
        }                                                                   \
        _Pragma("unroll")                                                   \
        for (int i = 0; i < 2; ++i) {              /* mask 4: 4 -> 2 */     \
            const float send = (kg & 4) ? acc[i] : acc[i + 2];              \
            const float keep = (kg & 4) ? acc[i + 2] : acc[i];              \
            acc[i] = keep + __shfl_xor(send, 4);                            \
        }                                                                   \
        {                                          /* mask 2: 2 -> 1 */     \
            const float send = (kg & 2) ? acc[0] : acc[1];                  \
            const float keep = (kg & 2) ? acc[1] : acc[0];                  \
            acc[0] = keep + __shfl_xor(send, 2);                            \
        }                                                                   \
        acc[0] += __shfl_xor(acc[0], 1);           /* mask 1 */             \
        const float hnew = fast_tanh(acc[0] + axv);                         \
        if (wr) hbuf[NXT][mycol] = hnew;                                    \
        __syncthreads();                                                    \
        axv   = ax_n;                                                       \
        tok_n = tok_nn;                                                     \
    }

    for (int t = 0; t < T_LEN; t += 2) {
        RNN_STEP(0, 1, t)
        RNN_STEP(1, 0, t + 1)
    }
#undef RNN_STEP

    // --- epilogue: out[b][c] = sum_j h[j] * clf_w[j][c] + clf_b[c] ---
    // After an even number of steps the final h is in hbuf[0].
    if (tid < HID) {
        const float h = hbuf[0][tid];
        sbuf[0][tid] = h * clfw[tid * N_CLS + 0];
        sbuf[1][tid] = h * clfw[tid * N_CLS + 1];
    }
    __syncthreads();
    if (tid < 64) {
        float v = sbuf[0][tid] + sbuf[0][tid + 64] +
                  sbuf[0][tid + 128] + sbuf[0][tid + 192];
#pragma unroll
        for (int off = 32; off > 0; off >>= 1) v += __shfl_xor(v, off);
        if (tid == 0) out[b * N_CLS + 0] = v + clfb[0];
    } else if (tid < 128) {
        const int l = tid - 64;
        float v = sbuf[1][l] + sbuf[1][l + 64] +
                  sbuf[1][l + 128] + sbuf[1][l + 192];
#pragma unroll
        for (int off = 32; off > 0; off >>= 1) v += __shfl_xor(v, off);
        if (l == 0) out[b * N_CLS + 1] = v + clfb[1];
    }
}

// ---------------------------------------------------------------------------
// Fallback (workspace too small for the 51.5 MB table).
// ---------------------------------------------------------------------------
__global__ __launch_bounds__(512, 2)
void rnn_fallback_kernel(const int*   __restrict__ batch,
                         const float* __restrict__ emb,
                         const float* __restrict__ wxw,
                         const float* __restrict__ wxb,
                         const float* __restrict__ whw,
                         const float* __restrict__ whb,
                         const float* __restrict__ clfw,
                         const float* __restrict__ clfb,
                         float*       __restrict__ out)
{
    const int b    = blockIdx.x;
    const int tid  = threadIdx.x;
    const int j    = tid >> 1;
    const int half = tid & 1;
    const int k0   = half * 128;

    __shared__ float hbuf[2][HID];
    __shared__ float ebuf[2][D_EMB];

    float w[128];
#pragma unroll
    for (int k = 0; k < 128; ++k)
        w[k] = whw[(size_t)(k0 + k) * HID + j];

    float wx[64];
#pragma unroll
    for (int d = 0; d < 64; ++d)
        wx[d] = wxw[(size_t)(half * 64 + d) * HID + j];

    const float bj  = whb[j];
    const float axb = wxb[j];

    if (tid < HID) hbuf[0][tid] = 0.f;

    const int* brow = batch + (size_t)b * T_LEN;

    int tok_n = brow[0];
    if (tid < D_EMB) ebuf[0][tid] = emb[(size_t)tok_n * D_EMB + tid];
    tok_n = brow[1];
    __syncthreads();

    float h_j = 0.f;
    int cur = 0;
    for (int t = 0; t < T_LEN; ++t) {
        const int nxt = cur ^ 1;
        const int tok_nn = (t + 2 < T_LEN) ? brow[t + 2] : 0;
        float ev = 0.f;
        if (t + 1 < T_LEN && tid < D_EMB)
            ev = emb[(size_t)tok_n * D_EMB + tid];

        float a0 = 0.f, a1 = 0.f, a2 = 0.f, a3 = 0.f;
        const float4* hv = (const float4*)&hbuf[cur][k0];
#pragma unroll
        for (int i = 0; i < 32; ++i) {
            float4 h4 = hv[i];
            a0 = fmaf(h4.x, w[4 * i + 0], a0);
            a1 = fmaf(h4.y, w[4 * i + 1], a1);
            a2 = fmaf(h4.z, w[4 * i + 2], a2);
            a3 = fmaf(h4.w, w[4 * i + 3], a3);
        }
        const float4* evv = (const float4*)&ebuf[cur][half * 64];
#pragma unroll
        for (int i = 0; i < 16; ++i) {
            float4 e4 = evv[i];
            a0 = fmaf(e4.x, wx[4 * i + 0], a0);
            a1 = fmaf(e4.y, wx[4 * i + 1], a1);
            a2 = fmaf(e4.z, wx[4 * i + 2], a2);
            a3 = fmaf(e4.w, wx[4 * i + 3], a3);
        }
        float s = (a0 + a1) + (a2 + a3);
        s += __shfl_xor(s, 1);

        h_j = fast_tanh(s + bj + axb);

        if (half == 0) hbuf[nxt][j] = h_j;
        if (t + 1 < T_LEN && tid < D_EMB) ebuf[nxt][tid] = ev;
        __syncthreads();

        tok_n = tok_nn;
        cur   = nxt;
    }

    if (half == 0) {
        hbuf[0][j] = h_j * clfw[j * N_CLS + 0];
        hbuf[1][j] = h_j * clfw[j * N_CLS + 1];
    }
    __syncthreads();
    if (tid < 64) {
        float v = hbuf[0][tid] + hbuf[0][tid + 64] +
                  hbuf[0][tid + 128] + hbuf[0][tid + 192];
#pragma unroll
        for (int off = 32; off > 0; off >>= 1) v += __shfl_xor(v, off);
        if (tid == 0) out[b * N_CLS + 0] = v + clfb[0];
    } else if (tid < 128) {
        const int l = tid - 64;
        float v = hbuf[1][l] + hbuf[1][l + 64] +
                  hbuf[1][l + 128] + hbuf[1][l + 192];
#pragma unroll
        for (int off = 32; off > 0; off >>= 1) v += __shfl_xor(v, off);
        if (l == 0) out[b * N_CLS + 1] = v + clfb[1];
    }
}

// ---------------------------------------------------------------------------
extern "C" void kernel_launch(void* const* d_in, const int* in_sizes, int n_in,
                              void* d_out, int out_size, void* d_ws, size_t ws_size,
                              hipStream_t stream)
{
    const int*   batch = (const int*)  d_in[0];
    const float* emb   = (const float*)d_in[1];
    const float* wxw   = (const float*)d_in[2];
    const float* wxb   = (const float*)d_in[3];
    const float* whw   = (const float*)d_in[4];
    const float* whb   = (const float*)d_in[5];
    const float* clfw  = (const float*)d_in[6];
    const float* clfb  = (const float*)d_in[7];
    float* out = (float*)d_out;

    const size_t tab_bytes = (size_t)VOCAB * HID * sizeof(float);
    if (ws_size >= tab_bytes) {
        float* tab = (float*)d_ws;
        tabax_kernel<<<(VOCAB + 31) / 32, 256, 0, stream>>>(emb, wxw, wxb, whb, tab);
        rnn_main_kernel<<<BSZ, 512, 0, stream>>>(batch, whw, clfw, clfb, tab, out);
    } else {
        rnn_fallback_kernel<<<BSZ, 512, 0, stream>>>(batch, emb, wxw, wxb, whw, whb,
                                                     clfw, clfb, out);
    }
}

// Round 11
// 1556.647 us; speedup vs baseline: 1.1221x; 1.1221x over previous
//
#include <hip/hip_runtime.h>
#include <hip/hip_bf16.h>

// Problem constants (match reference).
#define VOCAB  50257
#define D_EMB  128
#define HID    256
#define N_CLS  2
#define BSZ    256
#define T_LEN  2048

// ---------------------------------------------------------------------------
// Kernel 1: tab[v][j] = sum_d emb_table[v][d] * wx_w[d][j] + wx_b[j] + wh_b[j]
// ---------------------------------------------------------------------------
__global__ __launch_bounds__(256)
void tabax_kernel(const float* __restrict__ emb,
                  const float* __restrict__ wxw,
                  const float* __restrict__ wxb,
                  const float* __restrict__ whb,
                  float* __restrict__ tab)
{
    const int j  = threadIdx.x;          // output unit 0..255
    const int v0 = blockIdx.x * 32;
    const int rows = min(32, VOCAB - v0);

    __shared__ float ebuf[32 * D_EMB];   // 16 KB
    for (int i = j; i < rows * D_EMB; i += 256)
        ebuf[i] = emb[(size_t)v0 * D_EMB + i];
    __syncthreads();

    float acc[32];
#pragma unroll
    for (int r = 0; r < 32; ++r) acc[r] = 0.f;

#pragma unroll 8
    for (int d = 0; d < D_EMB; ++d) {
        float wxv = wxw[d * HID + j];    // coalesced
#pragma unroll
        for (int r = 0; r < 32; ++r)
            acc[r] = fmaf(ebuf[r * D_EMB + d], wxv, acc[r]); // LDS broadcast
    }

    const float bb = wxb[j] + whb[j];
    for (int r = 0; r < rows; ++r)
        tab[(size_t)(v0 + r) * HID + j] = acc[r] + bb;       // coalesced
}

__device__ __forceinline__ float fast_tanh(float x) {
    float e2 = __expf(2.f * x);
    return 1.f - 2.f / (e2 + 1.f);
}

// ---------------------------------------------------------------------------
// Kernel 2 (main): one block per batch row, 1024 threads (16 waves, 4/SIMD).
// Thread (cg = tid>>4, kg = tid&15) owns cols [cg*4, cg*4+4) over k in
// [kg*16, kg*16+16): W[4][4][4] = 64 f32 per thread. Per-thread live set
// ~110 regs < 128/wave budget at 4 waves/SIMD -- sized to stay under the
// RA's AGPR-stash threshold (R7/R9/R10: 128 weights/thread -> VGPR_Count=84
// + ~128 v_accvgpr_read copies per step; gfx950 VOP2 can't source AGPRs).
// Each swizzled ds_read_b128 of h feeds 16 FMAs. k-reduce over 16 lanes =
// sel-pair halving tree (5 shfl + 6 sel + 5 add); lanes (kg&3)==0 write
// col c0+((kg>>2)&3). 4 waves/SIMD doubles TLP vs the 512-thread version.
// Bank swizzle rot=(kg>>2)&3: 2 addrs per bank-quad = conflict-free
// (measured 0 conflicts with the identical scheme in R7/R9).
// ---------------------------------------------------------------------------
__global__ __launch_bounds__(1024, 1)
void rnn_main_kernel(const int*   __restrict__ batch,
                     const float* __restrict__ whw,
                     const float* __restrict__ clfw,
                     const float* __restrict__ clfb,
                     const float* __restrict__ ax_tab,
                     float*       __restrict__ out)
{
    const int b   = blockIdx.x;
    const int tid = threadIdx.x;
    const int kg  = tid & 15;            // k-group: k in [kg*16, kg*16+16)
    const int cg  = tid >> 4;            // col-group: cols [cg*4, cg*4+4)
    const int c0  = cg * 4;
    const int kb  = kg * 16;
    const int rot = (kg >> 2) & 3;       // bank-swizzle rotation

    __shared__ float hbuf[2][HID];       // double-buffered hidden state
    __shared__ float sbuf[2][HID];       // epilogue scratch

    // --- one-time weight load: W[e][m][i] = wh_w[kb+((e+rot)&3)*4+m][c0+i] ---
    float W[4][4][4];
#pragma unroll
    for (int e = 0; e < 4; ++e) {
        const int swz = (e + rot) & 3;
#pragma unroll
        for (int m = 0; m < 4; ++m) {
            const int k = kb + swz * 4 + m;
            const float4 w4 = *(const float4*)&whw[(size_t)k * HID + c0];
            W[e][m][0] = w4.x; W[e][m][1] = w4.y;
            W[e][m][2] = w4.z; W[e][m][3] = w4.w;
        }
    }
    // Pin: asm redefines each value -> no rematerialization inside the loop.
#pragma unroll
    for (int e = 0; e < 4; ++e)
#pragma unroll
        for (int m = 0; m < 4; ++m)
            asm volatile("" : "+v"(W[e][m][0]), "+v"(W[e][m][1]),
                              "+v"(W[e][m][2]), "+v"(W[e][m][3]));

    // LDS byte offsets of the 4 swizzled float4 reads (within one h buffer).
    int lds_off[4];
#pragma unroll
    for (int e = 0; e < 4; ++e) lds_off[e] = kg * 64 + ((e + rot) & 3) * 16;

    const int  mycol = c0 + ((kg >> 2) & 3);   // column this lane finalizes
    const bool wr    = (kg & 3) == 0;          // 1 of 4 dup lanes writes

    if (tid < HID) hbuf[0][tid] = 0.f;

    const int* brow = batch + (size_t)b * T_LEN;
    int tok_n = brow[0];
    float axv = ax_tab[(size_t)tok_n * HID + mycol];   // ax for t=0
    tok_n = brow[1];
    __syncthreads();

#define RNN_STEP(CUR, NXT, TT)                                              \
    {                                                                       \
        const int tok_nn = ((TT) + 2 < T_LEN) ? brow[(TT) + 2] : 0;         \
        const float ax_n = ax_tab[(size_t)tok_n * HID + mycol];             \
        float acc[4];                                                       \
        const char* hb = (const char*)&hbuf[CUR][0];                        \
        {   /* e = 0 initializes acc */                                     \
            const float4 h4 = *(const float4*)(hb + lds_off[0]);            \
            const float hm[4] = {h4.x, h4.y, h4.z, h4.w};                   \
            _Pragma("unroll")                                               \
            for (int i = 0; i < 4; ++i) acc[i] = hm[0] * W[0][0][i];        \
            _Pragma("unroll")                                               \
            for (int m = 1; m < 4; ++m)                                     \
                _Pragma("unroll")                                           \
                for (int i = 0; i < 4; ++i)                                 \
                    acc[i] = fmaf(hm[m], W[0][m][i], acc[i]);               \
        }                                                                   \
        _Pragma("unroll")                                                   \
        for (int e = 1; e < 4; ++e) {                                       \
            const float4 h4 = *(const float4*)(hb + lds_off[e]);            \
            const float hm[4] = {h4.x, h4.y, h4.z, h4.w};                   \
            _Pragma("unroll")                                               \
            for (int m = 0; m < 4; ++m)                                     \
                _Pragma("unroll")                                           \
                for (int i = 0; i < 4; ++i)                                 \
                    acc[i] = fmaf(hm[m], W[e][m][i], acc[i]);               \
        }                                                                   \
        /* sel-pair halving tree over the 16 kg lanes */                    \
        _Pragma("unroll")                                                   \
        for (int i = 0; i < 2; ++i) {              /* mask 8: 4 -> 2 */     \
            const float send = (kg & 8) ? acc[i] : acc[i + 2];              \
            const float keep = (kg & 8) ? acc[i + 2] : acc[i];              \
            acc[i] = keep + __shfl_xor(send, 8);                            \
        }                                                                   \
        {                                          /* mask 4: 2 -> 1 */     \
            const float send = (kg & 4) ? acc[0] : acc[1];                  \
            const float keep = (kg & 4) ? acc[1] : acc[0];                  \
            acc[0] = keep + __shfl_xor(send, 4);                            \
        }                                                                   \
        acc[0] += __shfl_xor(acc[0], 2);           /* mask 2 */             \
        acc[0] += __shfl_xor(acc[0], 1);           /* mask 1 */             \
        const float hnew = fast_tanh(acc[0] + axv);                         \
        if (wr) hbuf[NXT][mycol] = hnew;                                    \
        __syncthreads();                                                    \
        axv   = ax_n;                                                       \
        tok_n = tok_nn;                                                     \
    }

    for (int t = 0; t < T_LEN; t += 2) {
        RNN_STEP(0, 1, t)
        RNN_STEP(1, 0, t + 1)
    }
#undef RNN_STEP

    // --- epilogue: out[b][c] = sum_j h[j] * clf_w[j][c] + clf_b[c] ---
    // After an even number of steps the final h is in hbuf[0].
    if (tid < HID) {
        const float h = hbuf[0][tid];
        sbuf[0][tid] = h * clfw[tid * N_CLS + 0];
        sbuf[1][tid] = h * clfw[tid * N_CLS + 1];
    }
    __syncthreads();
    if (tid < 64) {
        float v = sbuf[0][tid] + sbuf[0][tid + 64] +
                  sbuf[0][tid + 128] + sbuf[0][tid + 192];
#pragma unroll
        for (int off = 32; off > 0; off >>= 1) v += __shfl_xor(v, off);
        if (tid == 0) out[b * N_CLS + 0] = v + clfb[0];
    } else if (tid < 128) {
        const int l = tid - 64;
        float v = sbuf[1][l] + sbuf[1][l + 64] +
                  sbuf[1][l + 128] + sbuf[1][l + 192];
#pragma unroll
        for (int off = 32; off > 0; off >>= 1) v += __shfl_xor(v, off);
        if (l == 0) out[b * N_CLS + 1] = v + clfb[1];
    }
}

// ---------------------------------------------------------------------------
// Fallback (workspace too small for the 51.5 MB table).
// ---------------------------------------------------------------------------
__global__ __launch_bounds__(512, 2)
void rnn_fallback_kernel(const int*   __restrict__ batch,
                         const float* __restrict__ emb,
                         const float* __restrict__ wxw,
                         const float* __restrict__ wxb,
                         const float* __restrict__ whw,
                         const float* __restrict__ whb,
                         const float* __restrict__ clfw,
                         const float* __restrict__ clfb,
                         float*       __restrict__ out)
{
    const int b    = blockIdx.x;
    const int tid  = threadIdx.x;
    const int j    = tid >> 1;
    const int half = tid & 1;
    const int k0   = half * 128;

    __shared__ float hbuf[2][HID];
    __shared__ float ebuf[2][D_EMB];

    float w[128];
#pragma unroll
    for (int k = 0; k < 128; ++k)
        w[k] = whw[(size_t)(k0 + k) * HID + j];

    float wx[64];
#pragma unroll
    for (int d = 0; d < 64; ++d)
        wx[d] = wxw[(size_t)(half * 64 + d) * HID + j];

    const float bj  = whb[j];
    const float axb = wxb[j];

    if (tid < HID) hbuf[0][tid] = 0.f;

    const int* brow = batch + (size_t)b * T_LEN;

    int tok_n = brow[0];
    if (tid < D_EMB) ebuf[0][tid] = emb[(size_t)tok_n * D_EMB + tid];
    tok_n = brow[1];
    __syncthreads();

    float h_j = 0.f;
    int cur = 0;
    for (int t = 0; t < T_LEN; ++t) {
        const int nxt = cur ^ 1;
        const int tok_nn = (t + 2 < T_LEN) ? brow[t + 2] : 0;
        float ev = 0.f;
        if (t + 1 < T_LEN && tid < D_EMB)
            ev = emb[(size_t)tok_n * D_EMB + tid];

        float a0 = 0.f, a1 = 0.f, a2 = 0.f, a3 = 0.f;
        const float4* hv = (const float4*)&hbuf[cur][k0];
#pragma unroll
        for (int i = 0; i < 32; ++i) {
            float4 h4 = hv[i];
            a0 = fmaf(h4.x, w[4 * i + 0], a0);
            a1 = fmaf(h4.y, w[4 * i + 1], a1);
            a2 = fmaf(h4.z, w[4 * i + 2], a2);
            a3 = fmaf(h4.w, w[4 * i + 3], a3);
        }
        const float4* evv = (const float4*)&ebuf[cur][half * 64];
#pragma unroll
        for (int i = 0; i < 16; ++i) {
            float4 e4 = evv[i];
            a0 = fmaf(e4.x, wx[4 * i + 0], a0);
            a1 = fmaf(e4.y, wx[4 * i + 1], a1);
            a2 = fmaf(e4.z, wx[4 * i + 2], a2);
            a3 = fmaf(e4.w, wx[4 * i + 3], a3);
        }
        float s = (a0 + a1) + (a2 + a3);
        s += __shfl_xor(s, 1);

        h_j = fast_tanh(s + bj + axb);

        if (half == 0) hbuf[nxt][j] = h_j;
        if (t + 1 < T_LEN && tid < D_EMB) ebuf[nxt][tid] = ev;
        __syncthreads();

        tok_n = tok_nn;
        cur   = nxt;
    }

    if (half == 0) {
        hbuf[0][j] = h_j * clfw[j * N_CLS + 0];
        hbuf[1][j] = h_j * clfw[j * N_CLS + 1];
    }
    __syncthreads();
    if (tid < 64) {
        float v = hbuf[0][tid] + hbuf[0][tid + 64] +
                  hbuf[0][tid + 128] + hbuf[0][tid + 192];
#pragma unroll
        for (int off = 32; off > 0; off >>= 1) v += __shfl_xor(v, off);
        if (tid == 0) out[b * N_CLS + 0] = v + clfb[0];
    } else if (tid < 128) {
        const int l = tid - 64;
        float v = hbuf[1][l] + hbuf[1][l + 64] +
                  hbuf[1][l + 128] + hbuf[1][l + 192];
#pragma unroll
        for (int off = 32; off > 0; off >>= 1) v += __shfl_xor(v, off);
        if (l == 0) out[b * N_CLS + 1] = v + clfb[1];
    }
}

// ---------------------------------------------------------------------------
extern "C" void kernel_launch(void* const* d_in, const int* in_sizes, int n_in,
                              void* d_out, int out_size, void* d_ws, size_t ws_size,
                              hipStream_t stream)
{
    const int*   batch = (const int*)  d_in[0];
    const float* emb   = (const float*)d_in[1];
    const float* wxw   = (const float*)d_in[2];
    const float* wxb   = (const float*)d_in[3];
    const float* whw   = (const float*)d_in[4];
    const float* whb   = (const float*)d_in[5];
    const float* clfw  = (const float*)d_in[6];
    const float* clfb  = (const float*)d_in[7];
    float* out = (float*)d_out;

    const size_t tab_bytes = (size_t)VOCAB * HID * sizeof(float);
    if (ws_size >= tab_bytes) {
        float* tab = (float*)d_ws;
        tabax_kernel<<<(VOCAB + 31) / 32, 256, 0, stream>>>(emb, wxw, wxb, whb, tab);
        rnn_main_kernel<<<BSZ, 1024, 0, stream>>>(batch, whw, clfw, clfb, tab, out);
    } else {
        rnn_fallback_kernel<<<BSZ, 512, 0, stream>>>(batch, emb, wxw, wxb, whw, whb,
                                                     clfw, clfb, out);
    }
}